// Round 8
// baseline (559.344 us; speedup 1.0000x reference)
//
#include <hip/hip_runtime.h>

#define EPS_C 0.01f

typedef __attribute__((ext_vector_type(8))) short short8;
typedef __attribute__((ext_vector_type(4))) float f32x4;
typedef __attribute__((ext_vector_type(4))) unsigned short u16x4;
typedef __attribute__((ext_vector_type(8))) unsigned short u16x8;

// ---------- workspace layout (float offsets) ----------
#define WS_H    0        // 320*320
#define WS_C    102400   // 256*256  P -> (block GJ) -> Pinv, in place
#define WS_T    167936   // 256*64
#define WS_R    184320   // 64*256
#define WS_W    200704   // 64*256
#define WS_E    217088   // 64*64
#define WS_CTR  221184   // barrier counter (1 u32)
#define WS_Y    233472   // 256*256
#define WS_RHS  299008   // 256*64
#define WS_D11  331776   // 64*64
#define WS_WFH  419840   // 256*352 u16 each  [A | B2 | 0 | B1]
#define WS_WFM  464896
#define WS_WFL  509952
#define WS_BBH  555008   // 64*288 u16 each (base B = [C1T^T | D12 | 0])
#define WS_BBM  564224
#define WS_BBL  573440
#define WS_WG   582656   // 65536*64 fp32

__device__ __forceinline__ unsigned short f2bf(float f) {
    unsigned int u = __float_as_uint(f);
    unsigned int r = (u + 0x7fffu + ((u >> 16) & 1u)) >> 16;
    return (unsigned short)r;
}
__device__ __forceinline__ float bf2f(unsigned short h) {
    return __uint_as_float(((unsigned int)h) << 16);
}
__device__ __forceinline__ void split1(float f, unsigned short& h, unsigned short& m, unsigned short& l) {
    h = f2bf(f);
    float r1 = f - bf2f(h);
    m = f2bf(r1);
    l = f2bf(r1 - bf2f(m));
}
__device__ __forceinline__ void split8(const float* v, short8& h8, short8& m8, short8& l8) {
#pragma unroll
    for (int j = 0; j < 8; ++j) {
        unsigned short h, m, l;
        split1(v[j], h, m, l);
        h8[j] = (short)h; m8[j] = (short)m; l8[j] = (short)l;
    }
}

// ---------------- setup: P and H builds ----------------
__global__ void k_build(const float* __restrict__ Xm, const float* __restrict__ XPm,
                        float* __restrict__ H, float* __restrict__ P) {
    int idx = blockIdx.x * 256 + threadIdx.x;
    if (idx < 102400) {
        int i = idx / 320, j = idx - i * 320;
        const float4* a = (const float4*)(Xm + i * 320);
        const float4* b = (const float4*)(Xm + j * 320);
        float s = 0.f;
        for (int k = 0; k < 80; ++k) {
            float4 va = a[k], vb = b[k];
            s += va.x * vb.x + va.y * vb.y + va.z * vb.z + va.w * vb.w;
        }
        H[idx] = (i == j) ? s + EPS_C : s;
    } else {
        idx -= 102400;
        if (idx < 65536) {
            int i = idx >> 8, j = idx & 255;
            const float4* a = (const float4*)(XPm + i * 256);
            const float4* b = (const float4*)(XPm + j * 256);
            float s = 0.f;
            for (int k = 0; k < 64; ++k) {
                float4 va = a[k], vb = b[k];
                s += va.x * vb.x + va.y * vb.y + va.z * vb.z + va.w * vb.w;
            }
            P[idx] = (i == j) ? s + EPS_C : s;
        }
    }
}

// ---------------- setup: derived + direct packs + ctr reset ----------------
__global__ void k_derived(const float* __restrict__ H, const float* __restrict__ Um,
                          const float* __restrict__ Y1, const float* __restrict__ B2,
                          const float* __restrict__ D12,
                          float* __restrict__ Y, float* __restrict__ RHS,
                          float* __restrict__ D11g,
                          unsigned short* __restrict__ Bh, unsigned short* __restrict__ Bm,
                          unsigned short* __restrict__ Bl,
                          unsigned short* __restrict__ Bbh, unsigned short* __restrict__ Bbm,
                          unsigned short* __restrict__ Bbl,
                          unsigned int* __restrict__ ctr) {
    int idx = blockIdx.x * 256 + threadIdx.x;
    if (idx < 65536) {
        int i = idx >> 8, j = idx & 255;
        Y[idx] = -0.5f * (H[i * 320 + j] + Y1[i * 256 + j] - Y1[j * 256 + i]);
        return;
    }
    idx -= 65536;
    if (idx < 16384) { // RHS = -H12 - U
        RHS[idx] = -H[(idx >> 6) * 320 + 256 + (idx & 63)] - Um[idx];
        return;
    }
    idx -= 16384;
    if (idx < 4096) { // D11
        int q = idx >> 6, j = idx & 63;
        float lam = 0.5f * H[(256 + q) * 320 + 256 + q];
        D11g[idx] = (j < q) ? -H[(256 + q) * 320 + 256 + j] / lam : 0.f;
        return;
    }
    idx -= 4096;
    if (idx < 8192) { // Wf pack cols 256..287: B2 (8) + pad (24)
        int o = idx >> 5, cc = idx & 31;
        float f = (cc < 8) ? B2[o * 8 + cc] : 0.f;
        unsigned short h, m, l;
        split1(f, h, m, l);
        size_t off = (size_t)o * 352 + 256 + cc;
        Bh[off] = h; Bm[off] = m; Bl[off] = l;
        return;
    }
    idx -= 8192;
    if (idx < 18432) { // Bb pack [C1T^T | D12 | 0], 64 x 288
        int q = idx / 288, k = idx - q * 288;
        float f;
        if (k < 256) {
            float lam = 0.5f * H[(256 + q) * 320 + 256 + q];
            f = Um[(size_t)k * 64 + q] / lam;
        } else if (k < 264) f = D12[(size_t)q * 8 + (k - 256)];
        else f = 0.f;
        unsigned short h, m, l;
        split1(f, h, m, l);
        Bbh[idx] = h; Bbm[idx] = m; Bbl[idx] = l;
        return;
    }
    idx -= 18432;
    if (idx == 0) *ctr = 0u;
}

// ---------------- fused GJ inversion + apply + pack (16 blocks, grid barrier) ----------------
__device__ __forceinline__ void gbar(unsigned int* ctr, unsigned int tgt) {
    __syncthreads();
    if (threadIdx.x == 0) {
        __threadfence();
        atomicAdd(ctr, 1u);
        while (atomicAdd(ctr, 0u) < tgt) { __builtin_amdgcn_s_sleep(8); }
        __threadfence();
    }
    __syncthreads();
}

__global__ void __launch_bounds__(256) k_setup2(float* __restrict__ C, float* __restrict__ E,
                                                float* __restrict__ T, float* __restrict__ R,
                                                float* __restrict__ W,
                                                const float* __restrict__ Y, const float* __restrict__ RHS,
                                                unsigned short* __restrict__ Bh, unsigned short* __restrict__ Bm,
                                                unsigned short* __restrict__ Bl,
                                                unsigned int* __restrict__ ctr) {
    __shared__ __align__(16) float S1[64 * 68];
    __shared__ __align__(16) float S2[64 * 68];
    const int tid = threadIdx.x;
    const int bid = blockIdx.x;
    const int ti = tid & 15, tj = tid >> 4;
    unsigned int ph = 0;
    for (int b = 0; b < 4; ++b) {
        // --- inv64 of diag block (block 0 only), M in S1 stride 65 ---
        if (bid == 0) {
            float* M = S1;
            const int row = tid >> 2, seg = tid & 3, c0 = seg * 16;
            const float* src = C + (size_t)(b * 64 + row) * 256 + b * 64 + c0;
#pragma unroll
            for (int t = 0; t < 4; ++t) {
                float4 v = *(const float4*)(src + t * 4);
                M[row * 65 + c0 + 4 * t + 0] = v.x; M[row * 65 + c0 + 4 * t + 1] = v.y;
                M[row * 65 + c0 + 4 * t + 2] = v.z; M[row * 65 + c0 + 4 * t + 3] = v.w;
            }
            for (int k = 0; k < 64; ++k) {
                __syncthreads();
                const float rinv = 1.0f / M[k * 65 + k];
                const float pk = M[row * 65 + k];
                float mk[16];
#pragma unroll
                for (int t = 0; t < 16; ++t) mk[t] = M[k * 65 + c0 + t];
                __syncthreads();
                if (row == k) {
#pragma unroll
                    for (int t = 0; t < 16; ++t) {
                        const int col = c0 + t;
                        M[k * 65 + col] = (col == k) ? rinv : mk[t] * rinv;
                    }
                } else {
                    const float f = -pk * rinv;
#pragma unroll
                    for (int t = 0; t < 16; ++t) {
                        const int col = c0 + t;
                        M[row * 65 + col] = (col == k) ? f : fmaf(f, mk[t], M[row * 65 + col]);
                    }
                }
            }
            __syncthreads();
            float* dstE = E + (size_t)row * 64 + c0;
            float* dstC = C + (size_t)(b * 64 + row) * 256 + b * 64 + c0;
#pragma unroll
            for (int t = 0; t < 4; ++t) {
                float4 v = {M[row * 65 + c0 + 4 * t + 0], M[row * 65 + c0 + 4 * t + 1],
                            M[row * 65 + c0 + 4 * t + 2], M[row * 65 + c0 + 4 * t + 3]};
                *(float4*)(dstE + t * 4) = v;
                *(float4*)(dstC + t * 4) = v;
            }
        }
        gbar(ctr, 16u * ++ph);
        // --- T/W/R (blocks 0..7) ---
        if (bid < 8) {
            const bool isT = bid < 4;
            const int blk = isT ? bid : bid - 4;
            for (int e = tid; e < 1024; e += 256) {
                int r = e >> 4, c4 = e & 15;
                float4 v = *(const float4*)&E[(size_t)r * 64 + c4 * 4];
                *(float4*)&S2[r * 68 + c4 * 4] = v;
            }
            for (int e = tid; e < 1024; e += 256) {
                int r = e >> 4, c4 = e & 15;
                float4 v;
                if (isT) v = *(const float4*)&C[(size_t)(blk * 64 + r) * 256 + b * 64 + c4 * 4];
                else {
                    v = *(const float4*)&C[(size_t)(b * 64 + r) * 256 + blk * 64 + c4 * 4];
                    *(float4*)&R[(size_t)r * 256 + blk * 64 + c4 * 4] = v;
                }
                *(float4*)&S1[r * 68 + c4 * 4] = v;
            }
            __syncthreads();
            float acc[4][4];
#pragma unroll
            for (int r = 0; r < 4; ++r)
#pragma unroll
                for (int d = 0; d < 4; ++d) acc[r][d] = 0.f;
            if (isT) {
                for (int kk = 0; kk < 64; ++kk) {
                    float a4[4], b4[4];
#pragma unroll
                    for (int d = 0; d < 4; ++d) { a4[d] = S1[(ti * 4 + d) * 68 + kk]; b4[d] = S2[kk * 68 + tj * 4 + d]; }
#pragma unroll
                    for (int r = 0; r < 4; ++r)
#pragma unroll
                        for (int d = 0; d < 4; ++d) acc[r][d] = fmaf(a4[r], b4[d], acc[r][d]);
                }
#pragma unroll
                for (int r = 0; r < 4; ++r) {
                    float4 v = {acc[r][0], acc[r][1], acc[r][2], acc[r][3]};
                    *(float4*)&T[(size_t)(blk * 64 + ti * 4 + r) * 64 + tj * 4] = v;
                }
            } else {
                for (int mm = 0; mm < 64; ++mm) {
                    float a4[4], b4[4];
#pragma unroll
                    for (int d = 0; d < 4; ++d) { a4[d] = S2[(ti * 4 + d) * 68 + mm]; b4[d] = S1[mm * 68 + tj * 4 + d]; }
#pragma unroll
                    for (int r = 0; r < 4; ++r)
#pragma unroll
                        for (int d = 0; d < 4; ++d) acc[r][d] = fmaf(a4[r], b4[d], acc[r][d]);
                }
#pragma unroll
                for (int r = 0; r < 4; ++r) {
                    float4 v = {acc[r][0], acc[r][1], acc[r][2], acc[r][3]};
                    *(float4*)&W[(size_t)(ti * 4 + r) * 256 + blk * 64 + tj * 4] = v;
                }
            }
        }
        gbar(ctr, 16u * ++ph);
        // --- update (all 16 blocks) ---
        {
            const int I = bid >> 2, J = bid & 3;
            if (I == b && J == b) {
            } else if (I == b) {
                const int r = tid >> 2, seg = tid & 3;
#pragma unroll
                for (int t = 0; t < 4; ++t) {
                    float4 v = *(const float4*)&W[(size_t)r * 256 + J * 64 + seg * 16 + t * 4];
                    *(float4*)&C[(size_t)(b * 64 + r) * 256 + J * 64 + seg * 16 + t * 4] = v;
                }
            } else if (J == b) {
                const int r = tid >> 2, seg = tid & 3;
#pragma unroll
                for (int t = 0; t < 4; ++t) {
                    float4 v = *(const float4*)&T[(size_t)(I * 64 + r) * 64 + seg * 16 + t * 4];
                    float4 nv = {-v.x, -v.y, -v.z, -v.w};
                    *(float4*)&C[(size_t)(I * 64 + r) * 256 + b * 64 + seg * 16 + t * 4] = nv;
                }
            } else {
                for (int e = tid; e < 1024; e += 256) {
                    int r = e >> 4, c4 = e & 15;
                    float4 v = *(const float4*)&T[(size_t)(I * 64 + r) * 64 + c4 * 4];
                    *(float4*)&S1[r * 68 + c4 * 4] = v;
                    float4 w = *(const float4*)&R[(size_t)r * 256 + J * 64 + c4 * 4];
                    *(float4*)&S2[r * 68 + c4 * 4] = w;
                }
                __syncthreads();
                float acc[4][4];
#pragma unroll
                for (int r = 0; r < 4; ++r) {
                    float4 cv = *(const float4*)&C[(size_t)(I * 64 + ti * 4 + r) * 256 + J * 64 + tj * 4];
                    acc[r][0] = cv.x; acc[r][1] = cv.y; acc[r][2] = cv.z; acc[r][3] = cv.w;
                }
                for (int kk = 0; kk < 64; ++kk) {
                    float a4[4], b4[4];
#pragma unroll
                    for (int d = 0; d < 4; ++d) { a4[d] = S1[(ti * 4 + d) * 68 + kk]; b4[d] = S2[kk * 68 + tj * 4 + d]; }
#pragma unroll
                    for (int r = 0; r < 4; ++r)
#pragma unroll
                        for (int d = 0; d < 4; ++d) acc[r][d] = fmaf(-a4[r], b4[d], acc[r][d]);
                }
#pragma unroll
                for (int r = 0; r < 4; ++r) {
                    float4 v = {acc[r][0], acc[r][1], acc[r][2], acc[r][3]};
                    *(float4*)&C[(size_t)(I * 64 + ti * 4 + r) * 256 + J * 64 + tj * 4] = v;
                }
            }
        }
        gbar(ctr, 16u * ++ph);
    }
    // --- apply PI @ [Y|RHS] and pack directly into Bh/Bm/Bl ---
    for (int t = bid; t < 20; t += 16) {
        const int i0 = (t / 5) * 64;
        const int c0 = (t % 5) * 64;
        float acc[4][4];
#pragma unroll
        for (int r = 0; r < 4; ++r)
#pragma unroll
            for (int d = 0; d < 4; ++d) acc[r][d] = 0.f;
        for (int kc = 0; kc < 4; ++kc) {
            __syncthreads();
            for (int e = tid; e < 1024; e += 256) {
                int i = e >> 4, k4 = e & 15;
                float4 v = *(const float4*)&C[(size_t)(i0 + i) * 256 + kc * 64 + k4 * 4];
                S1[(k4 * 4 + 0) * 68 + i] = v.x;
                S1[(k4 * 4 + 1) * 68 + i] = v.y;
                S1[(k4 * 4 + 2) * 68 + i] = v.z;
                S1[(k4 * 4 + 3) * 68 + i] = v.w;
                float4 w;
                if (c0 < 256) w = *(const float4*)&Y[(size_t)(kc * 64 + i) * 256 + c0 + k4 * 4];
                else          w = *(const float4*)&RHS[(size_t)(kc * 64 + i) * 64 + k4 * 4];
                *(float4*)&S2[i * 68 + k4 * 4] = w;
            }
            __syncthreads();
            for (int kk = 0; kk < 64; ++kk) {
                float4 pv = *(const float4*)&S1[kk * 68 + ti * 4];
                float4 gv = *(const float4*)&S2[kk * 68 + tj * 4];
                float p4[4] = {pv.x, pv.y, pv.z, pv.w};
                float g4[4] = {gv.x, gv.y, gv.z, gv.w};
#pragma unroll
                for (int r = 0; r < 4; ++r)
#pragma unroll
                    for (int d = 0; d < 4; ++d) acc[r][d] = fmaf(p4[r], g4[d], acc[r][d]);
            }
        }
        const int pc0 = (c0 < 256) ? c0 : 288;
#pragma unroll
        for (int r = 0; r < 4; ++r)
#pragma unroll
            for (int d = 0; d < 4; ++d) {
                unsigned short h, m, l;
                split1(acc[r][d], h, m, l);
                size_t off = (size_t)(i0 + ti * 4 + r) * 352 + pc0 + tj * 4 + d;
                Bh[off] = h; Bm[off] = m; Bl[off] = l;
            }
        __syncthreads();
    }
}

// ---------------- main 1a: base = [x|u|0] @ Bb^T + bv (x-only LDS, 3 blk/CU) ----------------
#define XSTR 264
__global__ void __launch_bounds__(256, 3) k_base(const float* __restrict__ x, const float* __restrict__ u,
                                                 const unsigned short* __restrict__ Bbh,
                                                 const unsigned short* __restrict__ Bbm,
                                                 const unsigned short* __restrict__ Bbl,
                                                 const float* __restrict__ bv,
                                                 float* __restrict__ wg) {
    __shared__ __align__(16) unsigned short Ah[32 * XSTR];
    __shared__ __align__(16) unsigned short Am[32 * XSTR];
    __shared__ __align__(16) unsigned short Al[32 * XSTR];
    const int tid = threadIdx.x;
    const int r0 = blockIdx.x * 32;
    {
        const float4* xg4 = (const float4*)(x + (size_t)r0 * 256);
#pragma unroll
        for (int i = 0; i < 8; ++i) {
            int e = tid + i * 256, r = e >> 6, c4 = e & 63;
            float4 v = xg4[e];
            float vv[4] = {v.x, v.y, v.z, v.w};
            u16x4 hv, mv, lv;
#pragma unroll
            for (int j = 0; j < 4; ++j) {
                unsigned short h, m, l;
                split1(vv[j], h, m, l);
                hv[j] = h; mv[j] = m; lv[j] = l;
            }
            *(u16x4*)&Ah[r * XSTR + c4 * 4] = hv;
            *(u16x4*)&Am[r * XSTR + c4 * 4] = mv;
            *(u16x4*)&Al[r * XSTR + c4 * 4] = lv;
        }
    }
    __syncthreads();
    const int lane = tid & 63, wid = tid >> 6;
    const int n0 = wid * 16;
    const int lr = lane & 15, lg = lane >> 4;
    const int lk = lg * 8;
    f32x4 acc[2];
    acc[0] = (f32x4){0.f, 0.f, 0.f, 0.f};
    acc[1] = (f32x4){0.f, 0.f, 0.f, 0.f};
    for (int kt = 0; kt < 8; ++kt) {
        const int ka = kt * 32 + lk;
        short8 a_h[2], a_m[2], a_l[2];
        a_h[0] = *(const short8*)&Ah[lr * XSTR + ka];
        a_h[1] = *(const short8*)&Ah[(16 + lr) * XSTR + ka];
        a_m[0] = *(const short8*)&Am[lr * XSTR + ka];
        a_m[1] = *(const short8*)&Am[(16 + lr) * XSTR + ka];
        a_l[0] = *(const short8*)&Al[lr * XSTR + ka];
        a_l[1] = *(const short8*)&Al[(16 + lr) * XSTR + ka];
        const size_t n = (size_t)(n0 + lr);
        short8 b_h = *(const short8*)&Bbh[n * 288 + ka];
        short8 b_m = *(const short8*)&Bbm[n * 288 + ka];
        short8 b_l = *(const short8*)&Bbl[n * 288 + ka];
#pragma unroll
        for (int m = 0; m < 2; ++m) {
            acc[m] = __builtin_amdgcn_mfma_f32_16x16x32_bf16(a_h[m], b_h, acc[m], 0, 0, 0);
            acc[m] = __builtin_amdgcn_mfma_f32_16x16x32_bf16(a_m[m], b_h, acc[m], 0, 0, 0);
            acc[m] = __builtin_amdgcn_mfma_f32_16x16x32_bf16(a_h[m], b_m, acc[m], 0, 0, 0);
            acc[m] = __builtin_amdgcn_mfma_f32_16x16x32_bf16(a_l[m], b_h, acc[m], 0, 0, 0);
            acc[m] = __builtin_amdgcn_mfma_f32_16x16x32_bf16(a_m[m], b_m, acc[m], 0, 0, 0);
            acc[m] = __builtin_amdgcn_mfma_f32_16x16x32_bf16(a_h[m], b_l, acc[m], 0, 0, 0);
        }
    }
    { // kt = 8: u (cols 256..263) + pad
        const int ka = 256 + lk;
        short8 a_h[2], a_m[2], a_l[2];
        if (lg == 0) {
            float vv[8];
            const float4* up = (const float4*)&u[(size_t)(r0 + lr) * 8];
            float4 v0 = up[0], v1 = up[1];
            vv[0] = v0.x; vv[1] = v0.y; vv[2] = v0.z; vv[3] = v0.w;
            vv[4] = v1.x; vv[5] = v1.y; vv[6] = v1.z; vv[7] = v1.w;
            split8(vv, a_h[0], a_m[0], a_l[0]);
            const float4* up2 = (const float4*)&u[(size_t)(r0 + 16 + lr) * 8];
            float4 w0 = up2[0], w1 = up2[1];
            vv[0] = w0.x; vv[1] = w0.y; vv[2] = w0.z; vv[3] = w0.w;
            vv[4] = w1.x; vv[5] = w1.y; vv[6] = w1.z; vv[7] = w1.w;
            split8(vv, a_h[1], a_m[1], a_l[1]);
        } else {
            short8 z = {0, 0, 0, 0, 0, 0, 0, 0};
            a_h[0] = z; a_h[1] = z; a_m[0] = z; a_m[1] = z; a_l[0] = z; a_l[1] = z;
        }
        const size_t n = (size_t)(n0 + lr);
        short8 b_h = *(const short8*)&Bbh[n * 288 + ka];
        short8 b_m = *(const short8*)&Bbm[n * 288 + ka];
        short8 b_l = *(const short8*)&Bbl[n * 288 + ka];
#pragma unroll
        for (int m = 0; m < 2; ++m) {
            acc[m] = __builtin_amdgcn_mfma_f32_16x16x32_bf16(a_h[m], b_h, acc[m], 0, 0, 0);
            acc[m] = __builtin_amdgcn_mfma_f32_16x16x32_bf16(a_m[m], b_h, acc[m], 0, 0, 0);
            acc[m] = __builtin_amdgcn_mfma_f32_16x16x32_bf16(a_h[m], b_m, acc[m], 0, 0, 0);
            acc[m] = __builtin_amdgcn_mfma_f32_16x16x32_bf16(a_l[m], b_h, acc[m], 0, 0, 0);
            acc[m] = __builtin_amdgcn_mfma_f32_16x16x32_bf16(a_m[m], b_m, acc[m], 0, 0, 0);
            acc[m] = __builtin_amdgcn_mfma_f32_16x16x32_bf16(a_h[m], b_l, acc[m], 0, 0, 0);
        }
    }
    const int lg2 = lane >> 4;
    const float bvv = bv[n0 + lr];
#pragma unroll
    for (int m = 0; m < 2; ++m)
#pragma unroll
        for (int j = 0; j < 4; ++j)
            wg[(size_t)(r0 + m * 16 + lg2 * 4 + j) * 64 + n0 + lr] = acc[m][j] + bvv;
}

// ---------------- main 1b: per-row recurrence (in place on wg) ----------------
__global__ void __launch_bounds__(256) k_rec(float* __restrict__ wg, const float* __restrict__ D11g) {
    __shared__ float D[64 * 64];
    const int tid = threadIdx.x;
#pragma unroll
    for (int t = 0; t < 16; ++t) D[tid + t * 256] = D11g[tid + t * 256];
    __syncthreads();
    const size_t r = (size_t)blockIdx.x * 256 + tid;
    float w[64];
    float* wr = wg + r * 64;
#pragma unroll
    for (int c = 0; c < 16; ++c) {
        float4 v = *(const float4*)&wr[c * 4];
        w[4 * c] = v.x; w[4 * c + 1] = v.y; w[4 * c + 2] = v.z; w[4 * c + 3] = v.w;
    }
    w[0] = fmaxf(w[0], 0.f);
#pragma unroll
    for (int i = 1; i < 64; ++i) {
        float s0 = w[i], s1 = 0.f, s2 = 0.f, s3 = 0.f;
#pragma unroll
        for (int j = 0; j + 3 < i; j += 4) {
            s0 = fmaf(w[j + 0], D[i * 64 + j + 0], s0);
            s1 = fmaf(w[j + 1], D[i * 64 + j + 1], s1);
            s2 = fmaf(w[j + 2], D[i * 64 + j + 2], s2);
            s3 = fmaf(w[j + 3], D[i * 64 + j + 3], s3);
        }
#pragma unroll
        for (int j = i & ~3; j < i; ++j) s0 = fmaf(w[j], D[i * 64 + j], s0);
        w[i] = fmaxf((s0 + s1) + (s2 + s3), 0.f);
    }
#pragma unroll
    for (int c = 0; c < 16; ++c) {
        float4 v = {w[4 * c], w[4 * c + 1], w[4 * c + 2], w[4 * c + 3]};
        *(float4*)&wr[c * 4] = v;
    }
}

// ---------------- main 2: out = [x|u|0|w] @ Wf^T (x-only LDS, 3 blk/CU) ----------------
__global__ void __launch_bounds__(256, 3) k_m2(const float* __restrict__ x, const float* __restrict__ wg,
                                               const float* __restrict__ u,
                                               const unsigned short* __restrict__ Bh,
                                               const unsigned short* __restrict__ Bm,
                                               const unsigned short* __restrict__ Bl,
                                               float* __restrict__ out) {
    __shared__ __align__(16) unsigned short Ah[32 * XSTR];
    __shared__ __align__(16) unsigned short Am[32 * XSTR];
    __shared__ __align__(16) unsigned short Al[32 * XSTR];
    const int tid = threadIdx.x;
    const int r0 = blockIdx.x * 32;
    {
        const float4* xg4 = (const float4*)(x + (size_t)r0 * 256);
#pragma unroll
        for (int i = 0; i < 8; ++i) {
            int e = tid + i * 256, r = e >> 6, c4 = e & 63;
            float4 v = xg4[e];
            float vv[4] = {v.x, v.y, v.z, v.w};
            u16x4 hv, mv, lv;
#pragma unroll
            for (int j = 0; j < 4; ++j) {
                unsigned short h, m, l;
                split1(vv[j], h, m, l);
                hv[j] = h; mv[j] = m; lv[j] = l;
            }
            *(u16x4*)&Ah[r * XSTR + c4 * 4] = hv;
            *(u16x4*)&Am[r * XSTR + c4 * 4] = mv;
            *(u16x4*)&Al[r * XSTR + c4 * 4] = lv;
        }
    }
    __syncthreads();
    const int lane = tid & 63, wid = tid >> 6;
    const int n0 = wid * 64;
    const int lr = lane & 15, lg = lane >> 4;
    const int lk = lg * 8;
    f32x4 acc[2][4];
#pragma unroll
    for (int m = 0; m < 2; ++m)
#pragma unroll
        for (int nf = 0; nf < 4; ++nf) acc[m][nf] = (f32x4){0.f, 0.f, 0.f, 0.f};

#define M2_MFMA6()                                                                               \
    for (int nf = 0; nf < 4; ++nf) {                                                             \
        for (int m = 0; m < 2; ++m) {                                                            \
            acc[m][nf] = __builtin_amdgcn_mfma_f32_16x16x32_bf16(a_h[m], b_h[nf], acc[m][nf], 0, 0, 0); \
            acc[m][nf] = __builtin_amdgcn_mfma_f32_16x16x32_bf16(a_m[m], b_h[nf], acc[m][nf], 0, 0, 0); \
            acc[m][nf] = __builtin_amdgcn_mfma_f32_16x16x32_bf16(a_h[m], b_m[nf], acc[m][nf], 0, 0, 0); \
            acc[m][nf] = __builtin_amdgcn_mfma_f32_16x16x32_bf16(a_l[m], b_h[nf], acc[m][nf], 0, 0, 0); \
            acc[m][nf] = __builtin_amdgcn_mfma_f32_16x16x32_bf16(a_m[m], b_m[nf], acc[m][nf], 0, 0, 0); \
            acc[m][nf] = __builtin_amdgcn_mfma_f32_16x16x32_bf16(a_h[m], b_l[nf], acc[m][nf], 0, 0, 0); \
        }                                                                                        \
    }

    for (int kt = 0; kt < 8; ++kt) {
        const int ka = kt * 32 + lk;
        short8 a_h[2], a_m[2], a_l[2];
        a_h[0] = *(const short8*)&Ah[lr * XSTR + ka];
        a_h[1] = *(const short8*)&Ah[(16 + lr) * XSTR + ka];
        a_m[0] = *(const short8*)&Am[lr * XSTR + ka];
        a_m[1] = *(const short8*)&Am[(16 + lr) * XSTR + ka];
        a_l[0] = *(const short8*)&Al[lr * XSTR + ka];
        a_l[1] = *(const short8*)&Al[(16 + lr) * XSTR + ka];
        short8 b_h[4], b_m[4], b_l[4];
#pragma unroll
        for (int nf = 0; nf < 4; ++nf) {
            const size_t n = (size_t)(n0 + nf * 16 + lr);
            b_h[nf] = *(const short8*)&Bh[n * 352 + ka];
            b_m[nf] = *(const short8*)&Bm[n * 352 + ka];
            b_l[nf] = *(const short8*)&Bl[n * 352 + ka];
        }
#pragma unroll
        M2_MFMA6()
    }
    { // kt = 8: u + pad
        const int ka = 256 + lk;
        short8 a_h[2], a_m[2], a_l[2];
        if (lg == 0) {
            float vv[8];
            const float4* up = (const float4*)&u[(size_t)(r0 + lr) * 8];
            float4 v0 = up[0], v1 = up[1];
            vv[0] = v0.x; vv[1] = v0.y; vv[2] = v0.z; vv[3] = v0.w;
            vv[4] = v1.x; vv[5] = v1.y; vv[6] = v1.z; vv[7] = v1.w;
            split8(vv, a_h[0], a_m[0], a_l[0]);
            const float4* up2 = (const float4*)&u[(size_t)(r0 + 16 + lr) * 8];
            float4 w0 = up2[0], w1 = up2[1];
            vv[0] = w0.x; vv[1] = w0.y; vv[2] = w0.z; vv[3] = w0.w;
            vv[4] = w1.x; vv[5] = w1.y; vv[6] = w1.z; vv[7] = w1.w;
            split8(vv, a_h[1], a_m[1], a_l[1]);
        } else {
            short8 z = {0, 0, 0, 0, 0, 0, 0, 0};
            a_h[0] = z; a_h[1] = z; a_m[0] = z; a_m[1] = z; a_l[0] = z; a_l[1] = z;
        }
        short8 b_h[4], b_m[4], b_l[4];
#pragma unroll
        for (int nf = 0; nf < 4; ++nf) {
            const size_t n = (size_t)(n0 + nf * 16 + lr);
            b_h[nf] = *(const short8*)&Bh[n * 352 + ka];
            b_m[nf] = *(const short8*)&Bm[n * 352 + ka];
            b_l[nf] = *(const short8*)&Bl[n * 352 + ka];
        }
#pragma unroll
        M2_MFMA6()
    }
    for (int kt = 9; kt < 11; ++kt) { // w tiles (8-product)
        const int ka = kt * 32 + lk;
        const int wc = (kt - 9) * 32 + lk;
        short8 a_h[2], a_m[2], a_l[2];
        {
            float vv[8];
            const float4* wp = (const float4*)&wg[(size_t)(r0 + lr) * 64 + wc];
            float4 v0 = wp[0], v1 = wp[1];
            vv[0] = v0.x; vv[1] = v0.y; vv[2] = v0.z; vv[3] = v0.w;
            vv[4] = v1.x; vv[5] = v1.y; vv[6] = v1.z; vv[7] = v1.w;
            split8(vv, a_h[0], a_m[0], a_l[0]);
            const float4* wp2 = (const float4*)&wg[(size_t)(r0 + 16 + lr) * 64 + wc];
            float4 w0 = wp2[0], w1 = wp2[1];
            vv[0] = w0.x; vv[1] = w0.y; vv[2] = w0.z; vv[3] = w0.w;
            vv[4] = w1.x; vv[5] = w1.y; vv[6] = w1.z; vv[7] = w1.w;
            split8(vv, a_h[1], a_m[1], a_l[1]);
        }
        short8 b_h[4], b_m[4], b_l[4];
#pragma unroll
        for (int nf = 0; nf < 4; ++nf) {
            const size_t n = (size_t)(n0 + nf * 16 + lr);
            b_h[nf] = *(const short8*)&Bh[n * 352 + ka];
            b_m[nf] = *(const short8*)&Bm[n * 352 + ka];
            b_l[nf] = *(const short8*)&Bl[n * 352 + ka];
        }
#pragma unroll
        for (int nf = 0; nf < 4; ++nf) {
#pragma unroll
            for (int m = 0; m < 2; ++m) {
                acc[m][nf] = __builtin_amdgcn_mfma_f32_16x16x32_bf16(a_h[m], b_h[nf], acc[m][nf], 0, 0, 0);
                acc[m][nf] = __builtin_amdgcn_mfma_f32_16x16x32_bf16(a_m[m], b_h[nf], acc[m][nf], 0, 0, 0);
                acc[m][nf] = __builtin_amdgcn_mfma_f32_16x16x32_bf16(a_h[m], b_m[nf], acc[m][nf], 0, 0, 0);
                acc[m][nf] = __builtin_amdgcn_mfma_f32_16x16x32_bf16(a_l[m], b_h[nf], acc[m][nf], 0, 0, 0);
                acc[m][nf] = __builtin_amdgcn_mfma_f32_16x16x32_bf16(a_m[m], b_m[nf], acc[m][nf], 0, 0, 0);
                acc[m][nf] = __builtin_amdgcn_mfma_f32_16x16x32_bf16(a_h[m], b_l[nf], acc[m][nf], 0, 0, 0);
                acc[m][nf] = __builtin_amdgcn_mfma_f32_16x16x32_bf16(a_m[m], b_l[nf], acc[m][nf], 0, 0, 0);
                acc[m][nf] = __builtin_amdgcn_mfma_f32_16x16x32_bf16(a_l[m], b_m[nf], acc[m][nf], 0, 0, 0);
            }
        }
    }
#pragma unroll
    for (int m = 0; m < 2; ++m)
#pragma unroll
        for (int nf = 0; nf < 4; ++nf)
#pragma unroll
            for (int j = 0; j < 4; ++j)
                out[(size_t)(r0 + m * 16 + lg * 4 + j) * 256 + n0 + nf * 16 + lr] = acc[m][nf][j];
}

extern "C" void kernel_launch(void* const* d_in, const int* in_sizes, int n_in,
                              void* d_out, int out_size, void* d_ws, size_t ws_size,
                              hipStream_t stream) {
    const float* x   = (const float*)d_in[0];
    const float* u   = (const float*)d_in[1];
    const float* Xm  = (const float*)d_in[2];
    const float* Um  = (const float*)d_in[3];
    const float* Y1  = (const float*)d_in[4];
    const float* XPm = (const float*)d_in[5];
    const float* B2  = (const float*)d_in[6];
    const float* D12 = (const float*)d_in[7];
    const float* bv  = (const float*)d_in[8];
    float* out = (float*)d_out;
    float* ws  = (float*)d_ws;

    float* H    = ws + WS_H;
    float* C    = ws + WS_C;
    float* T    = ws + WS_T;
    float* R    = ws + WS_R;
    float* W    = ws + WS_W;
    float* E    = ws + WS_E;
    float* Y    = ws + WS_Y;
    float* RHS  = ws + WS_RHS;
    float* D11g = ws + WS_D11;
    unsigned int* ctr = (unsigned int*)(ws + WS_CTR);
    unsigned short* Bh  = (unsigned short*)(ws + WS_WFH);
    unsigned short* Bm  = (unsigned short*)(ws + WS_WFM);
    unsigned short* Bl  = (unsigned short*)(ws + WS_WFL);
    unsigned short* Bbh = (unsigned short*)(ws + WS_BBH);
    unsigned short* Bbm = (unsigned short*)(ws + WS_BBM);
    unsigned short* Bbl = (unsigned short*)(ws + WS_BBL);
    float* wg = ws + WS_WG;

    k_build<<<656, 256, 0, stream>>>(Xm, XPm, H, C);
    k_derived<<<441, 256, 0, stream>>>(H, Um, Y1, B2, D12, Y, RHS, D11g,
                                       Bh, Bm, Bl, Bbh, Bbm, Bbl, ctr);
    k_base<<<2048, 256, 0, stream>>>(x, u, Bbh, Bbm, Bbl, bv, wg);
    k_rec<<<256, 256, 0, stream>>>(wg, D11g);
    k_setup2<<<16, 256, 0, stream>>>(C, E, T, R, W, Y, RHS, Bh, Bm, Bl, ctr);
    k_m2<<<2048, 256, 0, stream>>>(x, wg, u, Bh, Bm, Bl, out);
}